// Round 6
// baseline (26.190 us; speedup 1.0000x reference)
//
#include <hip/hip_runtime.h>

namespace ct {

constexpr double H   = 0.01;
constexpr double A21 = 0.161;
constexpr double A31 = -0.008480655492356989, A32 = 0.335480655492357;
constexpr double A41 = 2.8971530571054935,  A42 = -6.359448489975075, A43 = 4.3622954328695815;
constexpr double A51 = 5.325864828439257,   A52 = -11.748883564062828, A53 = 7.4955393428898365, A54 = -0.09249506636175525;
constexpr double A61 = 5.86145544294642,    A62 = -12.92096931784711,  A63 = 8.159367898576159,  A64 = -0.071584973281401, A65 = -0.028269050394068383;
constexpr double B1 = 0.09646076681806523,  B2 = 0.01, B3 = 0.4798896504144996, B4 = 1.379008574103742, B5 = -3.290069515436081, B6 = 2.324710524099774;

// constexpr exp: range-reduce to |r| <= ln2/2, Taylor, scale by 2^n
constexpr double cexp(double x) {
    const double LN2 = 0.69314718055994530942;
    double t = x / LN2;
    int n = (int)(t >= 0.0 ? t + 0.5 : t - 0.5);
    double r = x - (double)n * LN2;
    double sum = 1.0, term = 1.0;
    for (int i = 1; i < 26; ++i) { term *= r / (double)i; sum += term; }
    if (n >= 0) { for (int i = 0; i <  n; ++i) sum *= 2.0; }
    else        { for (int i = 0; i < -n; ++i) sum *= 0.5; }
    return sum;
}

struct Pair { double u, d; };

constexpr Pair rk(double yu, double yd, const double* F) {
    double k1u = yd, k1d = -25.0*yu - 10.0*yd + F[0];
    double tu = yu + H*(A21*k1u), td = yd + H*(A21*k1d);
    double k2u = td, k2d = -25.0*tu - 10.0*td + F[1];
    tu = yu + H*(A31*k1u + A32*k2u); td = yd + H*(A31*k1d + A32*k2d);
    double k3u = td, k3d = -25.0*tu - 10.0*td + F[2];
    tu = yu + H*(A41*k1u + A42*k2u + A43*k3u);
    td = yd + H*(A41*k1d + A42*k2d + A43*k3d);
    double k4u = td, k4d = -25.0*tu - 10.0*td + F[3];
    tu = yu + H*(A51*k1u + A52*k2u + A53*k3u + A54*k4u);
    td = yd + H*(A51*k1d + A52*k2d + A53*k3d + A54*k4d);
    double k5u = td, k5d = -25.0*tu - 10.0*td + F[4];
    tu = yu + H*(A61*k1u + A62*k2u + A63*k3u + A64*k4u + A65*k5u);
    td = yd + H*(A61*k1d + A62*k2d + A63*k3d + A64*k4d + A65*k5d);
    double k6u = td, k6d = -25.0*tu - 10.0*td + F[5];
    double ou = yu + H*(B1*k1u + B2*k2u + B3*k3u + B4*k4u + B5*k5u + B6*k6u);
    double od = yd + H*(B1*k1d + B2*k2d + B3*k3d + B4*k4d + B5*k5d + B6*k6d);
    return {ou, od};
}

struct alignas(16) CoefTab { float c[50][8]; };

constexpr CoefTab make_coefs() {
    CoefTab T{};
    double vu[6] = {}, vd[6] = {};
    for (int i = 0; i < 6; ++i) {
        double F[6] = {0,0,0,0,0,0};
        F[i] = 1.0;
        Pair pr = rk(0.0, 0.0, F);
        vu[i] = pr.u; vd[i] = pr.d;
    }
    double Fz[6] = {0,0,0,0,0,0};
    Pair mc0 = rk(1.0, 0.0, Fz);
    Pair mc1 = rk(0.0, 1.0, Fz);
    double m00 = mc0.u, m10 = mc0.d, m01 = mc1.u, m11 = mc1.d;

    double gam[6] = {};
    double k1 = -1.0; gam[0] = 1.0;
    gam[1] = 1.0 + H*A21*k1;                                            double k2 = -gam[1];
    gam[2] = 1.0 + H*(A31*k1 + A32*k2);                                 double k3 = -gam[2];
    gam[3] = 1.0 + H*(A41*k1 + A42*k2 + A43*k3);                        double k4 = -gam[3];
    gam[4] = 1.0 + H*(A51*k1 + A52*k2 + A53*k3 + A54*k4);               double k5 = -gam[4];
    gam[5] = 1.0 + H*(A61*k1 + A62*k2 + A63*k3 + A64*k4 + A65*k5);      double k6 = -gam[5];
    double r = 1.0 + H*(B1*k1 + B2*k2 + B3*k3 + B4*k4 + B5*k5 + B6*k6);

    double C[4] = {}, Hh[4] = {};
    for (int k = 0; k < 4; ++k) { C[k] = cexp(-(double)k / 3.0); Hh[k] = 4.0 / C[k]; }

    double gvu = 0.0, gvd = 0.0;
    for (int i = 0; i < 6; ++i) { gvu += vu[i]; gvd += vd[i]; }
    gvu *= 25.0; gvd *= 25.0;

    double Su[7] = {1,0,0,0,0,0,0};
    double Sd[7] = {0,1,0,0,0,0,0};
    for (int j = 0; j < 7; ++j) T.c[0][j] = (float)Su[j];
    T.c[0][7] = 0.0f;

    double p = 1.0;
    int save = 1;
    for (int n = 0; n < 98; ++n) {
        double Qu[4] = {}, Qd[4] = {};
        for (int i = 0; i < 6; ++i) {
            double pi = gam[i] * p;
            double ps[4] = {}; double ss = 0.0;
            for (int k = 0; k < 4; ++k) {
                double d0 = pi - C[k];
                ps[k] = cexp(-Hh[k] * d0 * d0);
                ss += ps[k];
            }
            double sc = pi / ss;
            for (int k = 0; k < 4; ++k) {
                double sk = ps[k] * sc;
                Qu[k] += vu[i] * sk;
                Qd[k] += vd[i] * sk;
            }
        }
        double nu[7] = {}, nd[7] = {};
        for (int j = 0; j < 7; ++j) {
            nu[j] = m00*Su[j] + m01*Sd[j];
            nd[j] = m10*Su[j] + m11*Sd[j];
        }
        nu[2] += gvu; nd[2] += gvd;
        for (int k = 0; k < 4; ++k) { nu[3+k] += Qu[k]; nd[3+k] += Qd[k]; }
        for (int j = 0; j < 7; ++j) { Su[j] = nu[j]; Sd[j] = nd[j]; }
        p *= r;
        if (n & 1) {
            for (int j = 0; j < 7; ++j) T.c[save][j] = (float)Su[j];
            T.c[save][7] = 0.0f;
            ++save;
        }
    }
    return T;
}

} // namespace ct

constexpr ct::CoefTab h_coef = ct::make_coefs();
__constant__ ct::CoefTab g_coef = h_coef;

// Wave <-> 8 consecutive batches (4096 waves total, ~4/SIMD).
// Lane l: dim-quad a4 = l&3, base row r0 = l>>2. Coefficient rows are
// lane-invariant registers; per batch: 7 feature loads, ~130 VALU,
// 4x 1KB-contiguous wave stores (32 stores / 25.6KB contiguous per wave).
__global__ __launch_bounds__(256, 4) void ndp_main(
    const float* __restrict__ init,   // (B, 32)
    const float* __restrict__ rbfw,   // (B, 64)
    const float* __restrict__ goals,  // (B, 16)
    float* __restrict__ out) {        // (B, 50, 16)
    const int l  = threadIdx.x & 63;
    const int wv = blockIdx.x * 4 + (threadIdx.x >> 6);   // 0..4095
    const int a4 = l & 3;
    const int r0 = l >> 2;

    // hoist this lane's 4 coefficient rows into registers
    float4 C0[4], C1[4];
    #pragma unroll
    for (int j = 0; j < 4; ++j) {
        const int r = (j == 3 && r0 >= 2) ? 0 : (r0 + j * 16);
        C0[j] = *reinterpret_cast<const float4*>(&g_coef.c[r][0]);
        C1[j] = *reinterpret_cast<const float4*>(&g_coef.c[r][4]);
    }
    const bool has4 = (r0 < 2);
    const int b0 = wv * 8;

    #pragma unroll
    for (int t = 0; t < 8; ++t) {
        const int b = b0 + t;
        const float4 u0  = *reinterpret_cast<const float4*>(&init[b * 32 + a4 * 4]);
        const float4 ud0 = *reinterpret_cast<const float4*>(&init[b * 32 + 16 + a4 * 4]);
        const float4 g4  = *reinterpret_cast<const float4*>(&goals[b * 16 + a4 * 4]);
        const float4 w0  = *reinterpret_cast<const float4*>(&rbfw[b * 64 + (4 * a4 + 0) * 4]);
        const float4 w1  = *reinterpret_cast<const float4*>(&rbfw[b * 64 + (4 * a4 + 1) * 4]);
        const float4 w2  = *reinterpret_cast<const float4*>(&rbfw[b * 64 + (4 * a4 + 2) * 4]);
        const float4 w3  = *reinterpret_cast<const float4*>(&rbfw[b * 64 + (4 * a4 + 3) * 4]);

        float4 gmu;
        gmu.x = g4.x - u0.x; gmu.y = g4.y - u0.y;
        gmu.z = g4.z - u0.z; gmu.w = g4.w - u0.w;
        float4 P0, P1, P2, P3;
        P0.x = gmu.x * w0.x; P0.y = gmu.y * w1.x; P0.z = gmu.z * w2.x; P0.w = gmu.w * w3.x;
        P1.x = gmu.x * w0.y; P1.y = gmu.y * w1.y; P1.z = gmu.z * w2.y; P1.w = gmu.w * w3.y;
        P2.x = gmu.x * w0.z; P2.y = gmu.y * w1.z; P2.z = gmu.z * w2.z; P2.w = gmu.w * w3.z;
        P3.x = gmu.x * w0.w; P3.y = gmu.y * w1.w; P3.z = gmu.z * w2.w; P3.w = gmu.w * w3.w;

        float* ob = out + (size_t)b * 800;
        #pragma unroll
        for (int j = 0; j < 4; ++j) {
            if (j < 3 || has4) {
                const float4 c0 = C0[j], c1 = C1[j];
                float4 v;
                v.x = c0.x*u0.x + c0.y*ud0.x + c0.z*g4.x + c0.w*P0.x + c1.x*P1.x + c1.y*P2.x + c1.z*P3.x;
                v.y = c0.x*u0.y + c0.y*ud0.y + c0.z*g4.y + c0.w*P0.y + c1.x*P1.y + c1.y*P2.y + c1.z*P3.y;
                v.z = c0.x*u0.z + c0.y*ud0.z + c0.z*g4.z + c0.w*P0.z + c1.x*P1.z + c1.y*P2.z + c1.z*P3.z;
                v.w = c0.x*u0.w + c0.y*ud0.w + c0.z*g4.w + c0.w*P0.w + c1.x*P1.w + c1.y*P2.w + c1.z*P3.w;
                *reinterpret_cast<float4*>(ob + (j * 64 + l) * 4) = v;
            }
        }
    }
}

extern "C" void kernel_launch(void* const* d_in, const int* in_sizes, int n_in,
                              void* d_out, int out_size, void* d_ws, size_t ws_size,
                              hipStream_t stream) {
    const float* init  = (const float*)d_in[0];
    const float* rbfw  = (const float*)d_in[1];
    const float* goals = (const float*)d_in[2];
    float* out = (float*)d_out;

    const int B = in_sizes[0] / 32;          // 32768
    // 4096 waves x 8 batches each
    ndp_main<<<B / 32, 256, 0, stream>>>(init, rbfw, goals, out);
}

// Round 7
// 24.601 us; speedup vs baseline: 1.0646x; 1.0646x over previous
//
#include <hip/hip_runtime.h>

namespace ct {

constexpr double H   = 0.01;
constexpr double A21 = 0.161;
constexpr double A31 = -0.008480655492356989, A32 = 0.335480655492357;
constexpr double A41 = 2.8971530571054935,  A42 = -6.359448489975075, A43 = 4.3622954328695815;
constexpr double A51 = 5.325864828439257,   A52 = -11.748883564062828, A53 = 7.4955393428898365, A54 = -0.09249506636175525;
constexpr double A61 = 5.86145544294642,    A62 = -12.92096931784711,  A63 = 8.159367898576159,  A64 = -0.071584973281401, A65 = -0.028269050394068383;
constexpr double B1 = 0.09646076681806523,  B2 = 0.01, B3 = 0.4798896504144996, B4 = 1.379008574103742, B5 = -3.290069515436081, B6 = 2.324710524099774;

// constexpr exp: range-reduce to |r| <= ln2/2, Taylor, scale by 2^n
constexpr double cexp(double x) {
    const double LN2 = 0.69314718055994530942;
    double t = x / LN2;
    int n = (int)(t >= 0.0 ? t + 0.5 : t - 0.5);
    double r = x - (double)n * LN2;
    double sum = 1.0, term = 1.0;
    for (int i = 1; i < 26; ++i) { term *= r / (double)i; sum += term; }
    if (n >= 0) { for (int i = 0; i <  n; ++i) sum *= 2.0; }
    else        { for (int i = 0; i < -n; ++i) sum *= 0.5; }
    return sum;
}

struct Pair { double u, d; };

constexpr Pair rk(double yu, double yd, const double* F) {
    double k1u = yd, k1d = -25.0*yu - 10.0*yd + F[0];
    double tu = yu + H*(A21*k1u), td = yd + H*(A21*k1d);
    double k2u = td, k2d = -25.0*tu - 10.0*td + F[1];
    tu = yu + H*(A31*k1u + A32*k2u); td = yd + H*(A31*k1d + A32*k2d);
    double k3u = td, k3d = -25.0*tu - 10.0*td + F[2];
    tu = yu + H*(A41*k1u + A42*k2u + A43*k3u);
    td = yd + H*(A41*k1d + A42*k2d + A43*k3d);
    double k4u = td, k4d = -25.0*tu - 10.0*td + F[3];
    tu = yu + H*(A51*k1u + A52*k2u + A53*k3u + A54*k4u);
    td = yd + H*(A51*k1d + A52*k2d + A53*k3d + A54*k4d);
    double k5u = td, k5d = -25.0*tu - 10.0*td + F[4];
    tu = yu + H*(A61*k1u + A62*k2u + A63*k3u + A64*k4u + A65*k5u);
    td = yd + H*(A61*k1d + A62*k2d + A63*k3d + A64*k4d + A65*k5d);
    double k6u = td, k6d = -25.0*tu - 10.0*td + F[5];
    double ou = yu + H*(B1*k1u + B2*k2u + B3*k3u + B4*k4u + B5*k5u + B6*k6u);
    double od = yd + H*(B1*k1d + B2*k2d + B3*k3d + B4*k4d + B5*k5d + B6*k6d);
    return {ou, od};
}

struct alignas(16) CoefTab { float c[50][8]; };

constexpr CoefTab make_coefs() {
    CoefTab T{};
    double vu[6] = {}, vd[6] = {};
    for (int i = 0; i < 6; ++i) {
        double F[6] = {0,0,0,0,0,0};
        F[i] = 1.0;
        Pair pr = rk(0.0, 0.0, F);
        vu[i] = pr.u; vd[i] = pr.d;
    }
    double Fz[6] = {0,0,0,0,0,0};
    Pair mc0 = rk(1.0, 0.0, Fz);
    Pair mc1 = rk(0.0, 1.0, Fz);
    double m00 = mc0.u, m10 = mc0.d, m01 = mc1.u, m11 = mc1.d;

    double gam[6] = {};
    double k1 = -1.0; gam[0] = 1.0;
    gam[1] = 1.0 + H*A21*k1;                                            double k2 = -gam[1];
    gam[2] = 1.0 + H*(A31*k1 + A32*k2);                                 double k3 = -gam[2];
    gam[3] = 1.0 + H*(A41*k1 + A42*k2 + A43*k3);                        double k4 = -gam[3];
    gam[4] = 1.0 + H*(A51*k1 + A52*k2 + A53*k3 + A54*k4);               double k5 = -gam[4];
    gam[5] = 1.0 + H*(A61*k1 + A62*k2 + A63*k3 + A64*k4 + A65*k5);      double k6 = -gam[5];
    double r = 1.0 + H*(B1*k1 + B2*k2 + B3*k3 + B4*k4 + B5*k5 + B6*k6);

    double C[4] = {}, Hh[4] = {};
    for (int k = 0; k < 4; ++k) { C[k] = cexp(-(double)k / 3.0); Hh[k] = 4.0 / C[k]; }

    double gvu = 0.0, gvd = 0.0;
    for (int i = 0; i < 6; ++i) { gvu += vu[i]; gvd += vd[i]; }
    gvu *= 25.0; gvd *= 25.0;

    double Su[7] = {1,0,0,0,0,0,0};
    double Sd[7] = {0,1,0,0,0,0,0};
    for (int j = 0; j < 7; ++j) T.c[0][j] = (float)Su[j];
    T.c[0][7] = 0.0f;

    double p = 1.0;
    int save = 1;
    for (int n = 0; n < 98; ++n) {
        double Qu[4] = {}, Qd[4] = {};
        for (int i = 0; i < 6; ++i) {
            double pi = gam[i] * p;
            double ps[4] = {}; double ss = 0.0;
            for (int k = 0; k < 4; ++k) {
                double d0 = pi - C[k];
                ps[k] = cexp(-Hh[k] * d0 * d0);
                ss += ps[k];
            }
            double sc = pi / ss;
            for (int k = 0; k < 4; ++k) {
                double sk = ps[k] * sc;
                Qu[k] += vu[i] * sk;
                Qd[k] += vd[i] * sk;
            }
        }
        double nu[7] = {}, nd[7] = {};
        for (int j = 0; j < 7; ++j) {
            nu[j] = m00*Su[j] + m01*Sd[j];
            nd[j] = m10*Su[j] + m11*Sd[j];
        }
        nu[2] += gvu; nd[2] += gvd;
        for (int k = 0; k < 4; ++k) { nu[3+k] += Qu[k]; nd[3+k] += Qd[k]; }
        for (int j = 0; j < 7; ++j) { Su[j] = nu[j]; Sd[j] = nd[j]; }
        p *= r;
        if (n & 1) {
            for (int j = 0; j < 7; ++j) T.c[save][j] = (float)Su[j];
            T.c[save][7] = 0.0f;
            ++save;
        }
    }
    return T;
}

} // namespace ct

constexpr ct::CoefTab h_coef = ct::make_coefs();
__constant__ ct::CoefTab g_coef = h_coef;

struct Feats { float4 u0, ud0, g4, w0, w1, w2, w3; };

__device__ __forceinline__ Feats load_feats(const float* __restrict__ init,
                                            const float* __restrict__ rbfw,
                                            const float* __restrict__ goals,
                                            int b, int a4) {
    Feats f;
    f.u0  = *reinterpret_cast<const float4*>(&init[b * 32 + a4 * 4]);
    f.ud0 = *reinterpret_cast<const float4*>(&init[b * 32 + 16 + a4 * 4]);
    f.g4  = *reinterpret_cast<const float4*>(&goals[b * 16 + a4 * 4]);
    f.w0  = *reinterpret_cast<const float4*>(&rbfw[b * 64 + (4 * a4 + 0) * 4]);
    f.w1  = *reinterpret_cast<const float4*>(&rbfw[b * 64 + (4 * a4 + 1) * 4]);
    f.w2  = *reinterpret_cast<const float4*>(&rbfw[b * 64 + (4 * a4 + 2) * 4]);
    f.w3  = *reinterpret_cast<const float4*>(&rbfw[b * 64 + (4 * a4 + 3) * 4]);
    return f;
}

// Measured-best config (R5): wave <-> 4 consecutive batches, 8192 waves
// (8/SIMD TLP), one-batch-ahead feature prefetch, coefficient rows in
// lane-invariant registers, 4x 1KB-contiguous wave stores per batch.
__global__ __launch_bounds__(256) void ndp_main(
    const float* __restrict__ init,   // (B, 32)
    const float* __restrict__ rbfw,   // (B, 64)
    const float* __restrict__ goals,  // (B, 16)
    float* __restrict__ out) {        // (B, 50, 16)
    const int l  = threadIdx.x & 63;
    const int wv = blockIdx.x * 4 + (threadIdx.x >> 6);   // 0..8191
    const int a4 = l & 3;
    const int r0 = l >> 2;

    // hoist this lane's 4 coefficient rows into registers
    float4 C0[4], C1[4];
    #pragma unroll
    for (int j = 0; j < 4; ++j) {
        const int r = (j == 3 && r0 >= 2) ? 0 : (r0 + j * 16);
        C0[j] = *reinterpret_cast<const float4*>(&g_coef.c[r][0]);
        C1[j] = *reinterpret_cast<const float4*>(&g_coef.c[r][4]);
    }
    const bool has4 = (r0 < 2);
    const int b0 = wv * 4;

    Feats f = load_feats(init, rbfw, goals, b0, a4);
    #pragma unroll
    for (int t = 0; t < 4; ++t) {
        Feats fn;
        if (t < 3) fn = load_feats(init, rbfw, goals, b0 + t + 1, a4);

        float4 gmu;
        gmu.x = f.g4.x - f.u0.x; gmu.y = f.g4.y - f.u0.y;
        gmu.z = f.g4.z - f.u0.z; gmu.w = f.g4.w - f.u0.w;
        float4 P0, P1, P2, P3;
        P0.x = gmu.x * f.w0.x; P0.y = gmu.y * f.w1.x; P0.z = gmu.z * f.w2.x; P0.w = gmu.w * f.w3.x;
        P1.x = gmu.x * f.w0.y; P1.y = gmu.y * f.w1.y; P1.z = gmu.z * f.w2.y; P1.w = gmu.w * f.w3.y;
        P2.x = gmu.x * f.w0.z; P2.y = gmu.y * f.w1.z; P2.z = gmu.z * f.w2.z; P2.w = gmu.w * f.w3.z;
        P3.x = gmu.x * f.w0.w; P3.y = gmu.y * f.w1.w; P3.z = gmu.z * f.w2.w; P3.w = gmu.w * f.w3.w;

        float* ob = out + (size_t)(b0 + t) * 800;
        #pragma unroll
        for (int j = 0; j < 4; ++j) {
            if (j < 3 || has4) {
                const float4 c0 = C0[j], c1 = C1[j];
                float4 v;
                v.x = c0.x*f.u0.x + c0.y*f.ud0.x + c0.z*f.g4.x + c0.w*P0.x + c1.x*P1.x + c1.y*P2.x + c1.z*P3.x;
                v.y = c0.x*f.u0.y + c0.y*f.ud0.y + c0.z*f.g4.y + c0.w*P0.y + c1.x*P1.y + c1.y*P2.y + c1.z*P3.y;
                v.z = c0.x*f.u0.z + c0.y*f.ud0.z + c0.z*f.g4.z + c0.w*P0.z + c1.x*P1.z + c1.y*P2.z + c1.z*P3.z;
                v.w = c0.x*f.u0.w + c0.y*f.ud0.w + c0.z*f.g4.w + c0.w*P0.w + c1.x*P1.w + c1.y*P2.w + c1.z*P3.w;
                *reinterpret_cast<float4*>(ob + (j * 64 + l) * 4) = v;
            }
        }
        f = fn;
    }
}

extern "C" void kernel_launch(void* const* d_in, const int* in_sizes, int n_in,
                              void* d_out, int out_size, void* d_ws, size_t ws_size,
                              hipStream_t stream) {
    const float* init  = (const float*)d_in[0];
    const float* rbfw  = (const float*)d_in[1];
    const float* goals = (const float*)d_in[2];
    float* out = (float*)d_out;

    const int B = in_sizes[0] / 32;          // 32768
    // 8192 waves x 4 batches each
    ndp_main<<<B / 16, 256, 0, stream>>>(init, rbfw, goals, out);
}